// Round 1
// baseline (2696.173 us; speedup 1.0000x reference)
//
#include <hip/hip_runtime.h>
#include <hip/hip_bf16.h>

// Problem: B=4, S=2048, D=1024, H=16, dk=64. All fp32.
// Pipeline: Q=x@Wq+bq ; K=x@Wk+bk ; V=x@Wv+bv  (three GEMMs, M=8192,N=1024,K=1024)
//           flash attention per (b,h,qtile) -> ctx (written in-place over Q buffer)
//           out = ctx@Wo + bo
// fp32 baseline on vector ALU (no fp32-input MFMA on CDNA4).

#define MH_B 4
#define MH_S 2048
#define MH_D 1024
#define MH_H 16
#define MH_DK 64

// ---------------------------------------------------------------------------
// GEMM: C[M,N] = A[M,K] @ B[K,N] + bias[N]     (64x64 tile, BK=16, 4x4 micro)
// ---------------------------------------------------------------------------
#define GT 64
#define GBK 16
#define GPAD 68   // 64+4: keeps float4 alignment (68*4 bytes % 16 == 0)

__global__ __launch_bounds__(256) void gemm_bias_kernel(
    const float* __restrict__ A, const float* __restrict__ B,
    const float* __restrict__ bias, float* __restrict__ C,
    int M, int N, int K)
{
    __shared__ float As[GBK][GPAD];   // transposed: As[k][m]
    __shared__ float Bs[GBK][GPAD];   // Bs[k][n]

    const int tid = threadIdx.x;
    const int tx = tid & 15;          // n micro index (0..15)
    const int ty = tid >> 4;          // m micro index (0..15)
    const int bm = blockIdx.y * GT;
    const int bn = blockIdx.x * GT;

    // A loader: row = tid/4 (0..63), 4 consecutive k at (tid%4)*4
    const int arow = tid >> 2;
    const int acol = (tid & 3) << 2;
    // B loader: k-row = tid/16 (0..15), 4 consecutive n at (tid%16)*4
    const int brow = tid >> 4;
    const int bcol = (tid & 15) << 2;

    float acc[4][4] = {};

    for (int k0 = 0; k0 < K; k0 += GBK) {
        const float4 av = *reinterpret_cast<const float4*>(
            &A[(size_t)(bm + arow) * K + k0 + acol]);
        As[acol + 0][arow] = av.x;
        As[acol + 1][arow] = av.y;
        As[acol + 2][arow] = av.z;
        As[acol + 3][arow] = av.w;
        *reinterpret_cast<float4*>(&Bs[brow][bcol]) =
            *reinterpret_cast<const float4*>(&B[(size_t)(k0 + brow) * N + bn + bcol]);
        __syncthreads();

#pragma unroll
        for (int kk = 0; kk < GBK; ++kk) {
            const float4 a4 = *reinterpret_cast<const float4*>(&As[kk][ty << 2]);
            const float4 b4 = *reinterpret_cast<const float4*>(&Bs[kk][tx << 2]);
            const float ar[4] = {a4.x, a4.y, a4.z, a4.w};
            const float br[4] = {b4.x, b4.y, b4.z, b4.w};
#pragma unroll
            for (int i = 0; i < 4; ++i)
#pragma unroll
                for (int j = 0; j < 4; ++j)
                    acc[i][j] = fmaf(ar[i], br[j], acc[i][j]);
        }
        __syncthreads();
    }

    const float4 bi = *reinterpret_cast<const float4*>(&bias[bn + (tx << 2)]);
    const float br[4] = {bi.x, bi.y, bi.z, bi.w};
#pragma unroll
    for (int i = 0; i < 4; ++i) {
        float4 o;
        o.x = acc[i][0] + br[0];
        o.y = acc[i][1] + br[1];
        o.z = acc[i][2] + br[2];
        o.w = acc[i][3] + br[3];
        *reinterpret_cast<float4*>(
            &C[(size_t)(bm + (ty << 2) + i) * N + bn + (tx << 2)]) = o;
    }
}

// ---------------------------------------------------------------------------
// Flash attention (fp32). One block = (b, h, 64-query tile). 256 threads.
// Thread (qg=tid>>4, kg=tid&15) owns 4x4 score micro-tile:
//   rows 4*qg..4*qg+3  x  keys 4*kg..4*kg+3 ; PV output dims 4*kg..4*kg+3.
// LDS tiles swizzled: float4-group g of row r stored at column (g ^ (r>>2)).
// ---------------------------------------------------------------------------
#define AT 64     // tile (queries and keys)
#define APAD 72   // row stride in floats (72*4 % 16 == 0)

__global__ __launch_bounds__(256) void attn_kernel(
    const float* Q, const float* K, const float* V, float* O)
{
    __shared__ float Qs[AT][APAD];
    __shared__ float Ks[AT][APAD];
    __shared__ float Vs[AT][APAD];
    __shared__ float Ps[AT][APAD];

    const int tid = threadIdx.x;
    const int h = blockIdx.x & 15;
    const int b = blockIdx.x >> 4;
    const int qt = blockIdx.y;

    // staging mapping: row = tid/4, quarter = tid%4 -> 4 float4 per thread
    const int srow = tid >> 2;
    const int sq = tid & 3;
    const int srq = srow >> 2;   // swizzle key for stores

    // compute mapping
    const int qg = tid >> 4;     // 0..15 : rows 4qg..4qg+3
    const int kg = tid & 15;     // 0..15 : keys/dims 4kg..4kg+3

    const size_t headoff = (size_t)(b * MH_S) * MH_D + h * MH_DK;
    const float* qptr = Q + headoff + (size_t)(qt * AT) * MH_D;

    // stage Q tile once
#pragma unroll
    for (int u = 0; u < 4; ++u) {
        const int g = (sq << 2) + u;
        *reinterpret_cast<float4*>(&Qs[srow][((g ^ srq) & 15) << 2]) =
            *reinterpret_cast<const float4*>(qptr + (size_t)srow * MH_D + (g << 2));
    }

    float m[4], l[4], oacc[4][4];
#pragma unroll
    for (int i = 0; i < 4; ++i) {
        m[i] = -INFINITY;
        l[i] = 0.f;
#pragma unroll
        for (int c = 0; c < 4; ++c) oacc[i][c] = 0.f;
    }

    for (int kt = 0; kt < MH_S / AT; ++kt) {
        __syncthreads();   // previous PV done before overwriting Ks/Vs
        const float* kptr = K + headoff + (size_t)(kt * AT) * MH_D;
        const float* vptr = V + headoff + (size_t)(kt * AT) * MH_D;
#pragma unroll
        for (int u = 0; u < 4; ++u) {
            const int g = (sq << 2) + u;
            const int cs = ((g ^ srq) & 15) << 2;
            *reinterpret_cast<float4*>(&Ks[srow][cs]) =
                *reinterpret_cast<const float4*>(kptr + (size_t)srow * MH_D + (g << 2));
            *reinterpret_cast<float4*>(&Vs[srow][cs]) =
                *reinterpret_cast<const float4*>(vptr + (size_t)srow * MH_D + (g << 2));
        }
        __syncthreads();

        // ---- scores: sc[i][j] = q_row(4qg+i) . k_row(4kg+j) ----
        float sc[4][4] = {};
#pragma unroll
        for (int d4 = 0; d4 < 16; ++d4) {
            float4 qv[4], kv[4];
            const int qcs = ((d4 ^ qg) & 15) << 2;
            const int kcs = ((d4 ^ kg) & 15) << 2;
#pragma unroll
            for (int i = 0; i < 4; ++i)
                qv[i] = *reinterpret_cast<const float4*>(&Qs[(qg << 2) + i][qcs]);
#pragma unroll
            for (int j = 0; j < 4; ++j)
                kv[j] = *reinterpret_cast<const float4*>(&Ks[(kg << 2) + j][kcs]);
#pragma unroll
            for (int i = 0; i < 4; ++i)
#pragma unroll
                for (int j = 0; j < 4; ++j) {
                    sc[i][j] = fmaf(qv[i].x, kv[j].x, sc[i][j]);
                    sc[i][j] = fmaf(qv[i].y, kv[j].y, sc[i][j]);
                    sc[i][j] = fmaf(qv[i].z, kv[j].z, sc[i][j]);
                    sc[i][j] = fmaf(qv[i].w, kv[j].w, sc[i][j]);
                }
        }

        // ---- online softmax ----
        float rmax[4], rsum[4], f[4], p[4][4];
#pragma unroll
        for (int i = 0; i < 4; ++i) {
            sc[i][0] *= 0.125f; sc[i][1] *= 0.125f;
            sc[i][2] *= 0.125f; sc[i][3] *= 0.125f;
            rmax[i] = fmaxf(fmaxf(sc[i][0], sc[i][1]), fmaxf(sc[i][2], sc[i][3]));
        }
#pragma unroll
        for (int off = 1; off < 16; off <<= 1)
#pragma unroll
            for (int i = 0; i < 4; ++i)
                rmax[i] = fmaxf(rmax[i], __shfl_xor(rmax[i], off));
#pragma unroll
        for (int i = 0; i < 4; ++i) {
            const float newm = fmaxf(m[i], rmax[i]);
            f[i] = __expf(m[i] - newm);
            m[i] = newm;
            rsum[i] = 0.f;
#pragma unroll
            for (int j = 0; j < 4; ++j) {
                p[i][j] = __expf(sc[i][j] - newm);
                rsum[i] += p[i][j];
            }
        }
#pragma unroll
        for (int off = 1; off < 16; off <<= 1)
#pragma unroll
            for (int i = 0; i < 4; ++i)
                rsum[i] += __shfl_xor(rsum[i], off);
#pragma unroll
        for (int i = 0; i < 4; ++i) {
            l[i] = l[i] * f[i] + rsum[i];
#pragma unroll
            for (int c = 0; c < 4; ++c) oacc[i][c] *= f[i];
            // write P row 4qg+i, key group kg (swizzle key = row>>2 = qg)
            *reinterpret_cast<float4*>(&Ps[(qg << 2) + i][((kg ^ qg) & 15) << 2]) =
                make_float4(p[i][0], p[i][1], p[i][2], p[i][3]);
        }
        __syncthreads();

        // ---- PV: oacc[i][c] += sum_j P[4qg+i][j] * V[j][4kg+c] ----
#pragma unroll
        for (int jg = 0; jg < 16; ++jg) {
            float4 pv[4], vv[4];
            const int pcs = ((jg ^ qg) & 15) << 2;
            const int vcs = ((kg ^ jg) & 15) << 2;
#pragma unroll
            for (int i = 0; i < 4; ++i)
                pv[i] = *reinterpret_cast<const float4*>(&Ps[(qg << 2) + i][pcs]);
#pragma unroll
            for (int jj = 0; jj < 4; ++jj)
                vv[jj] = *reinterpret_cast<const float4*>(&Vs[(jg << 2) + jj][vcs]);
#pragma unroll
            for (int i = 0; i < 4; ++i) {
                const float pr[4] = {pv[i].x, pv[i].y, pv[i].z, pv[i].w};
#pragma unroll
                for (int jj = 0; jj < 4; ++jj) {
                    oacc[i][0] = fmaf(pr[jj], vv[jj].x, oacc[i][0]);
                    oacc[i][1] = fmaf(pr[jj], vv[jj].y, oacc[i][1]);
                    oacc[i][2] = fmaf(pr[jj], vv[jj].z, oacc[i][2]);
                    oacc[i][3] = fmaf(pr[jj], vv[jj].w, oacc[i][3]);
                }
            }
        }
    }

    // ---- epilogue: normalize and store ctx (in [B*S, H*dk] layout) ----
    float* optr = O + headoff + (size_t)(qt * AT) * MH_D;
#pragma unroll
    for (int i = 0; i < 4; ++i) {
        const float inv = 1.f / l[i];
        float4 o;
        o.x = oacc[i][0] * inv;
        o.y = oacc[i][1] * inv;
        o.z = oacc[i][2] * inv;
        o.w = oacc[i][3] * inv;
        *reinterpret_cast<float4*>(optr + (size_t)((qg << 2) + i) * MH_D + (kg << 2)) = o;
    }
}

// ---------------------------------------------------------------------------
extern "C" void kernel_launch(void* const* d_in, const int* in_sizes, int n_in,
                              void* d_out, int out_size, void* d_ws, size_t ws_size,
                              hipStream_t stream) {
    const float* x  = (const float*)d_in[0];
    const float* Wq = (const float*)d_in[1];
    const float* bq = (const float*)d_in[2];
    const float* Wk = (const float*)d_in[3];
    const float* bk = (const float*)d_in[4];
    const float* Wv = (const float*)d_in[5];
    const float* bv = (const float*)d_in[6];
    const float* Wo = (const float*)d_in[7];
    const float* bo = (const float*)d_in[8];
    float* out = (float*)d_out;

    const int M = MH_B * MH_S;   // 8192
    const int N = MH_D;          // 1024
    const int K = MH_D;          // 1024

    float* Qb = (float*)d_ws;                    // 32 MB
    float* Kb = Qb + (size_t)M * N;              // 32 MB
    float* Vb = Kb + (size_t)M * N;              // 32 MB  (total 96 MB)

    dim3 gblk(256);
    dim3 ggrid(N / GT, M / GT);                  // (16, 128)
    hipLaunchKernelGGL(gemm_bias_kernel, ggrid, gblk, 0, stream, x, Wq, bq, Qb, M, N, K);
    hipLaunchKernelGGL(gemm_bias_kernel, ggrid, gblk, 0, stream, x, Wk, bk, Kb, M, N, K);
    hipLaunchKernelGGL(gemm_bias_kernel, ggrid, gblk, 0, stream, x, Wv, bv, Vb, M, N, K);

    dim3 agrid(MH_B * MH_H, MH_S / AT);          // (64, 32)
    hipLaunchKernelGGL(attn_kernel, agrid, gblk, 0, stream, Qb, Kb, Vb, Qb /*ctx in-place*/);

    hipLaunchKernelGGL(gemm_bias_kernel, ggrid, gblk, 0, stream, Qb, Wo, bo, out, M, N, K);
}

// Round 2
// 416.499 us; speedup vs baseline: 6.4734x; 6.4734x over previous
//
#include <hip/hip_runtime.h>
#include <hip/hip_bf16.h>

// MHSA: B=4,S=2048,D=1024,H=16,dk=64. fp32 in/out, bf16 MFMA compute.
// Pipeline:
//   convert   : x (fp32)  -> xb (bf16)
//   transpose : Wq,Wk,Wv,Wo (fp32 [K,N]) -> Wt (bf16 [N,K], 4 concatenated)
//   gemm<0>   : Qb = xb@Wq+bq   (bf16 [M,D])
//   gemm<0>   : Kb = xb@Wk+bk   (bf16 [M,D])
//   gemm<2>   : Vt = (xb@Wv+bv)^T per head -> bf16 [B][H][dk][S]
//   attn      : flash attention (MFMA) -> ctx bf16 [M,D]
//   gemm<1>   : out = ctx@Wo+bo (fp32 [M,D])
// All LDS tiles: [rows][64 bf16] with 16B-slot swizzle slot^=(row&7)  (T2).

#define MH_B 4
#define MH_S 2048
#define MH_D 1024
#define MH_H 16
#define MH_DK 64

typedef __bf16 bf16_t;
typedef bf16_t bf16x8 __attribute__((ext_vector_type(8)));
typedef bf16_t bf16x4 __attribute__((ext_vector_type(4)));
typedef float  f32x4  __attribute__((ext_vector_type(4)));

// ---------------------------------------------------------------------------
// fp32 -> bf16 elementwise convert (vectorized float4 in, bf16x4 out)
// ---------------------------------------------------------------------------
__global__ __launch_bounds__(256) void convert_bf16_kernel(
    const float* __restrict__ in, bf16_t* __restrict__ out, int n4)
{
    for (int i = blockIdx.x * 256 + threadIdx.x; i < n4; i += gridDim.x * 256) {
        float4 v = ((const float4*)in)[i];
        bf16x4 o;
        o[0] = (bf16_t)v.x; o[1] = (bf16_t)v.y;
        o[2] = (bf16_t)v.z; o[3] = (bf16_t)v.w;
        ((bf16x4*)out)[i] = o;
    }
}

// ---------------------------------------------------------------------------
// Transposed convert of the 4 weight matrices: Wt[z][n][k] = (bf16)W_z[k][n]
// ---------------------------------------------------------------------------
__global__ __launch_bounds__(256) void transpose_w_kernel(
    const float* __restrict__ W0, const float* __restrict__ W1,
    const float* __restrict__ W2, const float* __restrict__ W3,
    bf16_t* __restrict__ out)
{
    const float* W = (blockIdx.z == 0) ? W0 : (blockIdx.z == 1) ? W1
                   : (blockIdx.z == 2) ? W2 : W3;
    bf16_t* O = out + (size_t)blockIdx.z * MH_D * MH_D;
    __shared__ float T[32][33];
    const int tx = threadIdx.x, ty = threadIdx.y;       // (32,8)
    const int k0 = blockIdx.y * 32, n0 = blockIdx.x * 32;
#pragma unroll
    for (int i = 0; i < 4; ++i)
        T[ty + i * 8][tx] = W[(size_t)(k0 + ty + i * 8) * MH_D + n0 + tx];
    __syncthreads();
#pragma unroll
    for (int i = 0; i < 4; ++i)
        O[(size_t)(n0 + ty + i * 8) * MH_D + k0 + tx] = (bf16_t)T[tx][ty + i * 8];
}

// ---------------------------------------------------------------------------
// bf16 MFMA GEMM: C[M,N] = A[M,K] @ Bt[N,K]^T + bias[N]
// 128x128 tile, BK=64, 256 thr (4 waves 2x2, 64x64/wave, 4x4 frags of 16x16).
// MODE 0: bf16 C[M,N]; MODE 1: f32 C[M,N]; MODE 2: bf16 V-transposed
//         Vt[b][h][d][s]  (N must be 1024, head-major columns)
// ---------------------------------------------------------------------------
template<int MODE>
__global__ __launch_bounds__(256) void gemm_mfma_kernel(
    const bf16_t* __restrict__ A, const bf16_t* __restrict__ Bt,
    const float* __restrict__ bias, void* __restrict__ Cout,
    int M, int N, int K)
{
    __shared__ bf16_t As[128 * 64];
    __shared__ bf16_t Bs[128 * 64];

    const int tid = threadIdx.x;
    const int lane = tid & 63, wid = tid >> 6;
    const int lr = lane & 15, lg = lane >> 4;
    const int wr = wid >> 1, wc = wid & 1;
    const int bm = blockIdx.y * 128, bn = blockIdx.x * 128;

    // staging: thread t -> row t>>1 (0..127), slots (t&1)*4 + u (16B each)
    const int srow = tid >> 1;
    const int sbase = (tid & 1) * 4;
    const int r7 = srow & 7;
    const int wbase = srow * 64;

    const bf16_t* Ag = A + (size_t)(bm + srow) * K;
    const bf16_t* Bg = Bt + (size_t)(bn + srow) * K;

    f32x4 acc[4][4];
#pragma unroll
    for (int i = 0; i < 4; ++i)
#pragma unroll
        for (int j = 0; j < 4; ++j) acc[i][j] = (f32x4){0.f, 0.f, 0.f, 0.f};

    bf16x8 ra[4], rb[4];
#pragma unroll
    for (int u = 0; u < 4; ++u) {
        ra[u] = *(const bf16x8*)&Ag[(sbase + u) * 8];
        rb[u] = *(const bf16x8*)&Bg[(sbase + u) * 8];
    }
#pragma unroll
    for (int u = 0; u < 4; ++u) {
        *(bf16x8*)&As[wbase + (((sbase + u) ^ r7) << 3)] = ra[u];
        *(bf16x8*)&Bs[wbase + (((sbase + u) ^ r7) << 3)] = rb[u];
    }
    __syncthreads();

    const int nk = K >> 6;
    for (int kt = 0; kt < nk; ++kt) {
        const bool pf = (kt + 1 < nk);
        if (pf) {
            const int k0 = (kt + 1) << 6;
#pragma unroll
            for (int u = 0; u < 4; ++u) {
                ra[u] = *(const bf16x8*)&Ag[k0 + (sbase + u) * 8];
                rb[u] = *(const bf16x8*)&Bg[k0 + (sbase + u) * 8];
            }
        }
#pragma unroll
        for (int kc = 0; kc < 2; ++kc) {
            bf16x8 af[4], bfr[4];
#pragma unroll
            for (int i = 0; i < 4; ++i) {
                const int arow = wr * 64 + i * 16 + lr;
                af[i] = *(const bf16x8*)&As[arow * 64 + ((((kc << 2) + lg) ^ (lr & 7)) << 3)];
                const int brow = wc * 64 + i * 16 + lr;
                bfr[i] = *(const bf16x8*)&Bs[brow * 64 + ((((kc << 2) + lg) ^ (lr & 7)) << 3)];
            }
#pragma unroll
            for (int i = 0; i < 4; ++i)
#pragma unroll
                for (int j = 0; j < 4; ++j)
                    acc[i][j] = __builtin_amdgcn_mfma_f32_16x16x32_bf16(
                        af[i], bfr[j], acc[i][j], 0, 0, 0);
        }
        __syncthreads();
        if (pf) {
#pragma unroll
            for (int u = 0; u < 4; ++u) {
                *(bf16x8*)&As[wbase + (((sbase + u) ^ r7) << 3)] = ra[u];
                *(bf16x8*)&Bs[wbase + (((sbase + u) ^ r7) << 3)] = rb[u];
            }
        }
        __syncthreads();
    }

    // epilogue: C/D layout col = lane&15, row = (lane>>4)*4 + reg  [m89/m91]
#pragma unroll
    for (int j = 0; j < 4; ++j) {
        const int n = bn + wc * 64 + j * 16 + lr;
        const float bj = bias[n];
#pragma unroll
        for (int i = 0; i < 4; ++i) {
            const int m0 = bm + wr * 64 + i * 16 + (lg << 2);
            if (MODE == 0) {
                bf16_t* C = (bf16_t*)Cout;
#pragma unroll
                for (int r = 0; r < 4; ++r)
                    C[(size_t)(m0 + r) * N + n] = (bf16_t)(acc[i][j][r] + bj);
            } else if (MODE == 1) {
                float* C = (float*)Cout;
#pragma unroll
                for (int r = 0; r < 4; ++r)
                    C[(size_t)(m0 + r) * N + n] = acc[i][j][r] + bj;
            } else {
                bf16_t* C = (bf16_t*)Cout;
                const int h = n >> 6, d = n & 63;
                const int bb = m0 >> 11, s0 = m0 & 2047;
                bf16x4 pk;
#pragma unroll
                for (int r = 0; r < 4; ++r) pk[r] = (bf16_t)(acc[i][j][r] + bj);
                *(bf16x4*)&C[(((size_t)(bb * MH_H + h) * MH_DK + d) << 11) + s0] = pk;
            }
        }
    }
}

// ---------------------------------------------------------------------------
// MFMA flash attention. Block = (b*H+h, q-tile of 64). 256 thr = 4 waves,
// wave w owns q rows w*16..w*16+15 (Q frags in registers whole kernel).
// kv-tile 64: K LDS [64 keys][64 dk], V LDS [64 d][64 keys] (from Vt global),
// P per-wave LDS [16 q][64 keys]. All swizzled slot^=(row&7).
// ---------------------------------------------------------------------------
__global__ __launch_bounds__(256) void attn_mfma_kernel(
    const bf16_t* __restrict__ Q, const bf16_t* __restrict__ Kg_,
    const bf16_t* __restrict__ Vt, bf16_t* __restrict__ ctx)
{
    __shared__ bf16_t Ks[64 * 64];
    __shared__ bf16_t Vs[64 * 64];
    __shared__ bf16_t Ps[4 * 16 * 64];

    const int tid = threadIdx.x;
    const int lane = tid & 63, wid = tid >> 6;
    const int lr = lane & 15, lg = lane >> 4;
    const int h = blockIdx.x & 15, b = blockIdx.x >> 4;
    const int qt = blockIdx.y;

    // Q fragments: lane holds Q[q = lr][k = kc*32 + lg*8 + e]
    const size_t qtok = (size_t)(b * MH_S + qt * 64 + wid * 16 + lr);
    bf16x8 qf[2];
    qf[0] = *(const bf16x8*)&Q[qtok * MH_D + h * 64 + (lg << 3)];
    qf[1] = *(const bf16x8*)&Q[qtok * MH_D + h * 64 + 32 + (lg << 3)];

    // staging: thread t -> row t>>2 (0..63), slots (t&3)*2 + u
    const int srow = tid >> 2;
    const int sb = (tid & 3) * 2;
    const int r7 = srow & 7;
    const int wbase = srow * 64;
    const bf16_t* Kgp = Kg_ + (size_t)(b * MH_S) * MH_D + h * 64 + (size_t)srow * MH_D;
    const bf16_t* Vgp = Vt + ((size_t)(b * MH_H + h) * MH_DK + srow) * MH_S;

    f32x4 oacc[4];
#pragma unroll
    for (int nf = 0; nf < 4; ++nf) oacc[nf] = (f32x4){0.f, 0.f, 0.f, 0.f};
    float mrun[4] = {-1e30f, -1e30f, -1e30f, -1e30f};
    float lrun[4] = {0.f, 0.f, 0.f, 0.f};

    bf16x8 rk[2], rv[2];
#pragma unroll
    for (int u = 0; u < 2; ++u) {
        rk[u] = *(const bf16x8*)&Kgp[(sb + u) * 8];
        rv[u] = *(const bf16x8*)&Vgp[(sb + u) * 8];
    }
#pragma unroll
    for (int u = 0; u < 2; ++u) {
        *(bf16x8*)&Ks[wbase + (((sb + u) ^ r7) << 3)] = rk[u];
        *(bf16x8*)&Vs[wbase + (((sb + u) ^ r7) << 3)] = rv[u];
    }
    __syncthreads();

    const int pbase = wid * 1024;   // per-wave P region (16 rows x 64)
    for (int kt = 0; kt < MH_S / 64; ++kt) {
        const bool pf = (kt + 1 < MH_S / 64);
        if (pf) {
            const int kv0 = (kt + 1) * 64;
#pragma unroll
            for (int u = 0; u < 2; ++u) {
                rk[u] = *(const bf16x8*)&Kgp[(size_t)kv0 * MH_D + (sb + u) * 8];
                rv[u] = *(const bf16x8*)&Vgp[kv0 + (sb + u) * 8];
            }
        }

        // ---- scores: lane holds S[q=lg*4+r][key=j*16+lr] in sc[j][r] ----
        f32x4 sc[4];
#pragma unroll
        for (int j = 0; j < 4; ++j) sc[j] = (f32x4){0.f, 0.f, 0.f, 0.f};
#pragma unroll
        for (int kc = 0; kc < 2; ++kc) {
            const int sl = (((kc << 2) + lg) ^ (lr & 7)) << 3;
#pragma unroll
            for (int j = 0; j < 4; ++j) {
                bf16x8 kf = *(const bf16x8*)&Ks[(j * 16 + lr) * 64 + sl];
                sc[j] = __builtin_amdgcn_mfma_f32_16x16x32_bf16(qf[kc], kf, sc[j], 0, 0, 0);
            }
        }

        // ---- online softmax (row = q, reduce over 16-lane group) ----
        float rmx[4];
#pragma unroll
        for (int j = 0; j < 4; ++j) sc[j] *= 0.125f;
#pragma unroll
        for (int r = 0; r < 4; ++r)
            rmx[r] = fmaxf(fmaxf(sc[0][r], sc[1][r]), fmaxf(sc[2][r], sc[3][r]));
#pragma unroll
        for (int off = 1; off < 16; off <<= 1)
#pragma unroll
            for (int r = 0; r < 4; ++r)
                rmx[r] = fmaxf(rmx[r], __shfl_xor(rmx[r], off));

        float fsc[4];
#pragma unroll
        for (int r = 0; r < 4; ++r) {
            const float mn = fmaxf(mrun[r], rmx[r]);
            fsc[r] = __expf(mrun[r] - mn);
            mrun[r] = mn;
        }
        float rsum[4] = {0.f, 0.f, 0.f, 0.f};
#pragma unroll
        for (int j = 0; j < 4; ++j)
#pragma unroll
            for (int r = 0; r < 4; ++r) {
                const float p = __expf(sc[j][r] - mrun[r]);
                rsum[r] += p;
                const int ql = (lg << 2) + r;
                const int key = j * 16 + lr;
                Ps[pbase + ql * 64 + ((((key >> 3) ^ (ql & 7)) << 3)) + (key & 7)] = (bf16_t)p;
            }
#pragma unroll
        for (int off = 1; off < 16; off <<= 1)
#pragma unroll
            for (int r = 0; r < 4; ++r) rsum[r] += __shfl_xor(rsum[r], off);
#pragma unroll
        for (int r = 0; r < 4; ++r) lrun[r] = lrun[r] * fsc[r] + rsum[r];
        f32x4 fv = {fsc[0], fsc[1], fsc[2], fsc[3]};
#pragma unroll
        for (int nf = 0; nf < 4; ++nf) oacc[nf] *= fv;

        // ---- PV: A = P (wave-local LDS, no barrier), B = V^T ----
#pragma unroll
        for (int kc = 0; kc < 2; ++kc) {
            const int sl = (((kc << 2) + lg) ^ (lr & 7)) << 3;
            bf16x8 pa = *(const bf16x8*)&Ps[pbase + lr * 64 + sl];
#pragma unroll
            for (int nf = 0; nf < 4; ++nf) {
                bf16x8 vf = *(const bf16x8*)&Vs[(nf * 16 + lr) * 64 + sl];
                oacc[nf] = __builtin_amdgcn_mfma_f32_16x16x32_bf16(pa, vf, oacc[nf], 0, 0, 0);
            }
        }

        __syncthreads();
        if (pf) {
#pragma unroll
            for (int u = 0; u < 2; ++u) {
                *(bf16x8*)&Ks[wbase + (((sb + u) ^ r7) << 3)] = rk[u];
                *(bf16x8*)&Vs[wbase + (((sb + u) ^ r7) << 3)] = rv[u];
            }
        }
        __syncthreads();
    }

    // ---- epilogue: ctx[token][h*64+d], lane holds (q=lg*4+r, d=nf*16+lr) ----
    float inv[4];
#pragma unroll
    for (int r = 0; r < 4; ++r) inv[r] = 1.f / lrun[r];
#pragma unroll
    for (int nf = 0; nf < 4; ++nf)
#pragma unroll
        for (int r = 0; r < 4; ++r) {
            const int token = qt * 64 + wid * 16 + (lg << 2) + r;
            const int d = nf * 16 + lr;
            ctx[(size_t)(b * MH_S + token) * MH_D + h * 64 + d] =
                (bf16_t)(oacc[nf][r] * inv[r]);
        }
}

// ---------------------------------------------------------------------------
extern "C" void kernel_launch(void* const* d_in, const int* in_sizes, int n_in,
                              void* d_out, int out_size, void* d_ws, size_t ws_size,
                              hipStream_t stream) {
    const float* x  = (const float*)d_in[0];
    const float* Wq = (const float*)d_in[1];
    const float* bq = (const float*)d_in[2];
    const float* Wk = (const float*)d_in[3];
    const float* bk = (const float*)d_in[4];
    const float* Wv = (const float*)d_in[5];
    const float* bv = (const float*)d_in[6];
    const float* Wo = (const float*)d_in[7];
    const float* bo = (const float*)d_in[8];

    const int M = MH_B * MH_S;   // 8192
    const int N = MH_D;          // 1024
    const int K = MH_D;          // 1024

    char* ws = (char*)d_ws;
    bf16_t* xb  = (bf16_t*)(ws);                              // 16 MB
    bf16_t* Wt  = (bf16_t*)(ws + (size_t)16 * 1048576);       //  8 MB (4 x [N][K])
    bf16_t* Qb  = (bf16_t*)(ws + (size_t)24 * 1048576);       // 16 MB
    bf16_t* Kb  = (bf16_t*)(ws + (size_t)40 * 1048576);       // 16 MB
    bf16_t* Vtb = (bf16_t*)(ws + (size_t)56 * 1048576);       // 16 MB
    bf16_t* ctx = (bf16_t*)(ws + (size_t)72 * 1048576);       // 16 MB -> 88 MB

    // convert x
    hipLaunchKernelGGL(convert_bf16_kernel, dim3(2048), dim3(256), 0, stream,
                       x, xb, M * K / 4);
    // transpose-convert the 4 weights
    hipLaunchKernelGGL(transpose_w_kernel, dim3(32, 32, 4), dim3(32, 8), 0, stream,
                       Wq, Wk, Wv, Wo, Wt);

    const size_t WSTRIDE = (size_t)MH_D * MH_D;
    dim3 gg(N / 128, M / 128);   // (8, 64)
    hipLaunchKernelGGL(gemm_mfma_kernel<0>, gg, dim3(256), 0, stream,
                       xb, Wt + 0 * WSTRIDE, bq, (void*)Qb, M, N, K);
    hipLaunchKernelGGL(gemm_mfma_kernel<0>, gg, dim3(256), 0, stream,
                       xb, Wt + 1 * WSTRIDE, bk, (void*)Kb, M, N, K);
    hipLaunchKernelGGL(gemm_mfma_kernel<2>, gg, dim3(256), 0, stream,
                       xb, Wt + 2 * WSTRIDE, bv, (void*)Vtb, M, N, K);

    hipLaunchKernelGGL(attn_mfma_kernel, dim3(MH_B * MH_H, MH_S / 64), dim3(256),
                       0, stream, Qb, Kb, Vtb, ctx);

    hipLaunchKernelGGL(gemm_mfma_kernel<1>, gg, dim3(256), 0, stream,
                       ctx, Wt + 3 * WSTRIDE, bo, d_out, M, N, K);
}

// Round 5
// 350.135 us; speedup vs baseline: 7.7004x; 1.1895x over previous
//
#include <hip/hip_runtime.h>
#include <hip/hip_bf16.h>

// MHSA: B=4,S=2048,D=1024,H=16,dk=64. fp32 in/out, bf16 MFMA compute.
//   convert   : x (fp32)  -> xb (bf16)
//   transpose : Wq,Wk,Wv,Wo (fp32 [K,N]) -> Wt (bf16 [N,K], 4 concatenated)
//   gemm<0>   : Qb = xb@Wq+bq ; Kb = xb@Wk+bk     (bf16 [M,D])
//   gemm<2>   : Vt = (xb@Wv+bv)^T per head -> bf16 [B][H][dk][S]
//   attn      : flash attention, swapped QK^T (S^T layout) -> ctx bf16 [M,D]
//   gemm<1>   : out = ctx@Wo+bo (fp32 [M,D])
// GEMM: m97 structure (global_load_lds w16, linear LDS, 2-barrier K-loop, XCD swz).
// Attn: KVBLK=128, in-lane softmax (q = lane&15), packed P b64 stores, XOR-swizzled LDS.

#define MH_B 4
#define MH_S 2048
#define MH_D 1024
#define MH_H 16
#define MH_DK 64

typedef __bf16 bf16_t;
typedef bf16_t bf16x8 __attribute__((ext_vector_type(8)));
typedef bf16_t bf16x4 __attribute__((ext_vector_type(4)));
typedef float  f32x4  __attribute__((ext_vector_type(4)));

__device__ __forceinline__ void gll16(const void* g, void* l) {
    __builtin_amdgcn_global_load_lds(
        (__attribute__((address_space(1))) void*)const_cast<void*>(g),
        (__attribute__((address_space(3))) void*)l, 16, 0, 0);
}

// ---------------------------------------------------------------------------
__global__ __launch_bounds__(256) void convert_bf16_kernel(
    const float* __restrict__ in, bf16_t* __restrict__ out, int n4)
{
    for (int i = blockIdx.x * 256 + threadIdx.x; i < n4; i += gridDim.x * 256) {
        float4 v = ((const float4*)in)[i];
        bf16x4 o;
        o[0] = (bf16_t)v.x; o[1] = (bf16_t)v.y;
        o[2] = (bf16_t)v.z; o[3] = (bf16_t)v.w;
        ((bf16x4*)out)[i] = o;
    }
}

// ---------------------------------------------------------------------------
__global__ __launch_bounds__(256) void transpose_w_kernel(
    const float* __restrict__ W0, const float* __restrict__ W1,
    const float* __restrict__ W2, const float* __restrict__ W3,
    bf16_t* __restrict__ out)
{
    const float* W = (blockIdx.z == 0) ? W0 : (blockIdx.z == 1) ? W1
                   : (blockIdx.z == 2) ? W2 : W3;
    bf16_t* O = out + (size_t)blockIdx.z * MH_D * MH_D;
    __shared__ float T[32][33];
    const int tx = threadIdx.x, ty = threadIdx.y;       // (32,8)
    const int k0 = blockIdx.y * 32, n0 = blockIdx.x * 32;
#pragma unroll
    for (int i = 0; i < 4; ++i)
        T[ty + i * 8][tx] = W[(size_t)(k0 + ty + i * 8) * MH_D + n0 + tx];
    __syncthreads();
#pragma unroll
    for (int i = 0; i < 4; ++i)
        O[(size_t)(n0 + ty + i * 8) * MH_D + k0 + tx] = (bf16_t)T[tx][ty + i * 8];
}

// ---------------------------------------------------------------------------
// bf16 MFMA GEMM: C[M,N] = A[M,K] @ Bt[N,K]^T + bias[N]
// 128x128 tile, BK=64, 4 waves 2x2. global_load_lds staging, linear LDS.
// MODE 0: bf16 C; MODE 1: f32 C; MODE 2: bf16 Vt[b][h][d][s] (N==1024).
// ---------------------------------------------------------------------------
template<int MODE>
__global__ __launch_bounds__(256) void gemm_mfma_kernel(
    const bf16_t* __restrict__ A, const bf16_t* __restrict__ Bt,
    const float* __restrict__ bias, void* __restrict__ Cout,
    int M, int N, int K)
{
    __shared__ bf16_t As[128 * 64];
    __shared__ bf16_t Bs[128 * 64];

    const int tid = threadIdx.x;
    const int lane = tid & 63, wid = tid >> 6;
    const int lr = lane & 15, lg = lane >> 4;
    const int wr = wid >> 1, wc = wid & 1;

    // bijective XCD swizzle (nwg multiple of 8)
    const int nx = gridDim.x;
    const int wg = blockIdx.y * nx + blockIdx.x;
    const int cpx = (nx * gridDim.y) >> 3;
    const int swz = (wg & 7) * cpx + (wg >> 3);
    const int bm = (swz / nx) * 128;
    const int bn = (swz % nx) * 128;

    // staging: chunk c = wid*4+u covers rows c*8..c*8+7; lane -> row c*8+(lane>>3),
    // k-slot lane&7 (16B). LDS dest linear: chunk base + lane*16B (HW).
    const int crow = lane >> 3;
    const int cslot = lane & 7;

    f32x4 acc[4][4];
#pragma unroll
    for (int i = 0; i < 4; ++i)
#pragma unroll
        for (int j = 0; j < 4; ++j) acc[i][j] = (f32x4){0.f, 0.f, 0.f, 0.f};

    const int nk = K >> 6;
    for (int kt = 0; kt < nk; ++kt) {
        const int k0 = kt << 6;
#pragma unroll
        for (int u = 0; u < 4; ++u) {
            const int c = wid * 4 + u;
            const int row = c * 8 + crow;
            gll16(&A[(size_t)(bm + row) * K + k0 + cslot * 8], &As[c * 512]);
            gll16(&Bt[(size_t)(bn + row) * K + k0 + cslot * 8], &Bs[c * 512]);
        }
        __syncthreads();   // compiler drains vmcnt(0) before barrier
#pragma unroll
        for (int kc = 0; kc < 2; ++kc) {
            bf16x8 af[4], bfr[4];
#pragma unroll
            for (int i = 0; i < 4; ++i) {
                af[i]  = *(const bf16x8*)&As[(wr * 64 + i * 16 + lr) * 64 + ((kc << 2) + lg) * 8];
                bfr[i] = *(const bf16x8*)&Bs[(wc * 64 + i * 16 + lr) * 64 + ((kc << 2) + lg) * 8];
            }
#pragma unroll
            for (int i = 0; i < 4; ++i)
#pragma unroll
                for (int j = 0; j < 4; ++j)
                    acc[i][j] = __builtin_amdgcn_mfma_f32_16x16x32_bf16(
                        af[i], bfr[j], acc[i][j], 0, 0, 0);
        }
        __syncthreads();
    }

    // epilogue: C/D layout col = lane&15, row = (lane>>4)*4 + reg  [m89/m91]
#pragma unroll
    for (int j = 0; j < 4; ++j) {
        const int n = bn + wc * 64 + j * 16 + lr;
        const float bj = bias[n];
#pragma unroll
        for (int i = 0; i < 4; ++i) {
            const int m0 = bm + wr * 64 + i * 16 + (lg << 2);
            if (MODE == 0) {
                bf16_t* C = (bf16_t*)Cout;
#pragma unroll
                for (int r = 0; r < 4; ++r)
                    C[(size_t)(m0 + r) * N + n] = (bf16_t)(acc[i][j][r] + bj);
            } else if (MODE == 1) {
                float* C = (float*)Cout;
#pragma unroll
                for (int r = 0; r < 4; ++r)
                    C[(size_t)(m0 + r) * N + n] = acc[i][j][r] + bj;
            } else {
                bf16_t* C = (bf16_t*)Cout;
                const int h = n >> 6, d = n & 63;
                const int bb = m0 >> 11, s0 = m0 & 2047;
                bf16x4 pk;
#pragma unroll
                for (int r = 0; r < 4; ++r) pk[r] = (bf16_t)(acc[i][j][r] + bj);
                *(bf16x4*)&C[(((size_t)(bb * MH_H + h) * MH_DK + d) << 11) + s0] = pk;
            }
        }
    }
}

// ---------------------------------------------------------------------------
// MFMA flash attention, swapped QK^T. Block = (b*H+h, 64-q tile), 4 waves,
// wave w owns q rows w*16..w*16+15. KVBLK=128.
//   scores: sc[j] = mfma(Kfrag_j, Qfrag)  ->  lane holds S^T[key=j*16+lg*4+r][q=lr]
//   softmax: in-lane over 32 keys + shfl_xor(16,32); m,l scalar (q = lr)
//   P: packed bf16x4 b64 stores to per-wave LDS [q=lr][key], XOR-swizzled
//   PV: mfma(Pfrag, Vfrag) -> oacc[nf][r] = O[q=lg*4+r][d=nf*16+lr]
// LDS swizzle everywhere: 16B-slot' = slot ^ (row&7), row%8 == lr%8 on reads.
// ---------------------------------------------------------------------------
#define KVB 128
#define NKT (MH_S / KVB)

__global__ __launch_bounds__(256) void attn_mfma_kernel(
    const bf16_t* __restrict__ Q, const bf16_t* __restrict__ Kg_,
    const bf16_t* __restrict__ Vt, bf16_t* __restrict__ ctx)
{
    __shared__ bf16_t Ks[KVB * 64];       // [key][dk]     16KB
    __shared__ bf16_t Vs[64 * KVB];       // [d][key]      16KB
    __shared__ bf16_t Ps[4 * 16 * KVB];   // per-wave [q][key] 16KB

    const int tid = threadIdx.x;
    const int lane = tid & 63, wid = tid >> 6;
    const int lr = lane & 15, lg = lane >> 4;
    const int l7 = lr & 7;
    const int h = blockIdx.x & 15, b = blockIdx.x >> 4;
    const int qt = blockIdx.y;

    // Q fragments (B-operand: lane holds Q[q=lr][k=kc*32+lg*8+e]), pre-scaled 1/8
    const size_t qtok = (size_t)(b * MH_S + qt * 64 + wid * 16 + lr);
    bf16x8 qf[2];
    qf[0] = *(const bf16x8*)&Q[qtok * MH_D + h * 64 + (lg << 3)];
    qf[1] = *(const bf16x8*)&Q[qtok * MH_D + h * 64 + 32 + (lg << 3)];
#pragma unroll
    for (int kc = 0; kc < 2; ++kc)
#pragma unroll
        for (int e = 0; e < 8; ++e)
            qf[kc][e] = (bf16_t)(0.125f * (float)qf[kc][e]);   // 2^-3: exact

    // staging: K 128 rows x 8 slots; V 64 rows x 16 slots (16B slots)
    const int krow = tid >> 1, ks0 = (tid & 1) << 2;
    const int vrow = tid >> 2, vs0 = (tid & 3) << 2;
    const bf16_t* Kgp = Kg_ + ((size_t)(b * MH_S) + krow) * MH_D + h * 64;
    const bf16_t* Vgp = Vt + ((size_t)(b * MH_H + h) * MH_DK + vrow) * MH_S;

    f32x4 oacc[4];
#pragma unroll
    for (int nf = 0; nf < 4; ++nf) oacc[nf] = (f32x4){0.f, 0.f, 0.f, 0.f};
    float mrun = -1e30f, lrun = 0.f;

    bf16x8 rk[4], rv[4];
#pragma unroll
    for (int u = 0; u < 4; ++u) {
        rk[u] = *(const bf16x8*)&Kgp[(ks0 + u) * 8];
        rv[u] = *(const bf16x8*)&Vgp[(vs0 + u) * 8];
    }
#pragma unroll
    for (int u = 0; u < 4; ++u) {
        *(bf16x8*)&Ks[krow * 64 + (((ks0 + u) ^ (krow & 7)) << 3)] = rk[u];
        *(bf16x8*)&Vs[vrow * KVB + (((vs0 + u) ^ (vrow & 7)) << 3)] = rv[u];
    }
    __syncthreads();

    const int pbase = wid * (16 * KVB);

    for (int kt = 0; kt < NKT; ++kt) {
        const bool pf = (kt + 1 < NKT);
        if (pf) {   // T14: issue next-tile loads before compute
            const int kv0 = (kt + 1) * KVB;
#pragma unroll
            for (int u = 0; u < 4; ++u) {
                rk[u] = *(const bf16x8*)&Kgp[(size_t)kv0 * MH_D + (ks0 + u) * 8];
                rv[u] = *(const bf16x8*)&Vgp[kv0 + (vs0 + u) * 8];
            }
        }

        // ---- QK^T (swapped): sc[j][r] = S[key=j*16+lg*4+r][q=lr] ----
        f32x4 sc[8];
#pragma unroll
        for (int j = 0; j < 8; ++j) sc[j] = (f32x4){0.f, 0.f, 0.f, 0.f};
#pragma unroll
        for (int kc = 0; kc < 2; ++kc) {
            const int sl = (((kc << 2) + lg) ^ l7) << 3;
#pragma unroll
            for (int j = 0; j < 8; ++j) {
                bf16x8 kf = *(const bf16x8*)&Ks[(j * 16 + lr) * 64 + sl];
                sc[j] = __builtin_amdgcn_mfma_f32_16x16x32_bf16(kf, qf[kc], sc[j], 0, 0, 0);
            }
        }

        // ---- softmax for q=lr over 128 keys (in-lane 32 + 2 shfl) ----
        float pmax = -1e30f;
#pragma unroll
        for (int j = 0; j < 8; ++j) {
            pmax = fmaxf(pmax, fmaxf(fmaxf(sc[j][0], sc[j][1]),
                                     fmaxf(sc[j][2], sc[j][3])));
        }
        pmax = fmaxf(pmax, __shfl_xor(pmax, 16));
        pmax = fmaxf(pmax, __shfl_xor(pmax, 32));
        const float mn = fmaxf(mrun, pmax);
        const float fsc = __expf(mrun - mn);
        mrun = mn;

        float rsum = 0.f;
#pragma unroll
        for (int j = 0; j < 8; ++j) {
            const float p0 = __expf(sc[j][0] - mn);
            const float p1 = __expf(sc[j][1] - mn);
            const float p2 = __expf(sc[j][2] - mn);
            const float p3 = __expf(sc[j][3] - mn);
            rsum += (p0 + p1) + (p2 + p3);
            bf16x4 p4;
            p4[0] = (bf16_t)p0; p4[1] = (bf16_t)p1;
            p4[2] = (bf16_t)p2; p4[3] = (bf16_t)p3;
            // row q=lr, keys j*16+lg*4..+3 -> 16B-slot 2j+(lg>>1), half lg&1
            const int slot = (2 * j + (lg >> 1)) ^ l7;
            *(bf16x4*)&Ps[pbase + lr * KVB + (slot << 3) + ((lg & 1) << 2)] = p4;
        }
        rsum += __shfl_xor(rsum, 16);
        rsum += __shfl_xor(rsum, 32);
        lrun = lrun * fsc + rsum;

        // broadcast rescale factor from q-lane (lr=q) to output rows q=lg*4+r
        f32x4 fv;
#pragma unroll
        for (int r = 0; r < 4; ++r) fv[r] = __shfl(fsc, (lg << 2) | r);
#pragma unroll
        for (int nf = 0; nf < 4; ++nf) oacc[nf] *= fv;

        // ---- PV: oacc += P[q][128keys] @ V^T[d][128keys] ----
#pragma unroll
        for (int kc = 0; kc < 4; ++kc) {
            const int sl = (((kc << 2) + lg) ^ l7) << 3;
            bf16x8 pa = *(const bf16x8*)&Ps[pbase + lr * KVB + sl];
#pragma unroll
            for (int nf = 0; nf < 4; ++nf) {
                bf16x8 vf = *(const bf16x8*)&Vs[(nf * 16 + lr) * KVB + sl];
                oacc[nf] = __builtin_amdgcn_mfma_f32_16x16x32_bf16(pa, vf, oacc[nf], 0, 0, 0);
            }
        }

        __syncthreads();
        if (pf) {
#pragma unroll
            for (int u = 0; u < 4; ++u) {
                *(bf16x8*)&Ks[krow * 64 + (((ks0 + u) ^ (krow & 7)) << 3)] = rk[u];
                *(bf16x8*)&Vs[vrow * KVB + (((vs0 + u) ^ (vrow & 7)) << 3)] = rv[u];
            }
        }
        __syncthreads();
    }

    // ---- epilogue: oacc[nf][r] = O[q=lg*4+r][d=nf*16+lr] ----
    f32x4 linv;
#pragma unroll
    for (int r = 0; r < 4; ++r) linv[r] = 1.f / __shfl(lrun, (lg << 2) | r);
#pragma unroll
    for (int nf = 0; nf < 4; ++nf)
#pragma unroll
        for (int r = 0; r < 4; ++r) {
            const int token = qt * 64 + wid * 16 + (lg << 2) + r;
            ctx[(size_t)(b * MH_S + token) * MH_D + h * 64 + nf * 16 + lr] =
                (bf16_t)(oacc[nf][r] * linv[r]);
        }
}

// ---------------------------------------------------------------------------
extern "C" void kernel_launch(void* const* d_in, const int* in_sizes, int n_in,
                              void* d_out, int out_size, void* d_ws, size_t ws_size,
                              hipStream_t stream) {
    const float* x  = (const float*)d_in[0];
    const float* Wq = (const float*)d_in[1];
    const float* bq = (const float*)d_in[2];
    const float* Wk = (const float*)d_in[3];
    const float* bk = (const float*)d_in[4];
    const float* Wv = (const float*)d_in[5];
    const float* bv = (const float*)d_in[6];
    const float* Wo = (const float*)d_in[7];
    const float* bo = (const float*)d_in[8];

    const int M = MH_B * MH_S;   // 8192
    const int N = MH_D;          // 1024
    const int K = MH_D;          // 1024

    char* ws = (char*)d_ws;
    bf16_t* xb  = (bf16_t*)(ws);                              // 16 MB
    bf16_t* Wt  = (bf16_t*)(ws + (size_t)16 * 1048576);       //  8 MB (4 x [N][K])
    bf16_t* Qb  = (bf16_t*)(ws + (size_t)24 * 1048576);       // 16 MB
    bf16_t* Kb  = (bf16_t*)(ws + (size_t)40 * 1048576);       // 16 MB
    bf16_t* Vtb = (bf16_t*)(ws + (size_t)56 * 1048576);       // 16 MB
    bf16_t* ctx = (bf16_t*)(ws + (size_t)72 * 1048576);       // 16 MB -> 88 MB

    hipLaunchKernelGGL(convert_bf16_kernel, dim3(2048), dim3(256), 0, stream,
                       x, xb, M * K / 4);
    hipLaunchKernelGGL(transpose_w_kernel, dim3(32, 32, 4), dim3(32, 8), 0, stream,
                       Wq, Wk, Wv, Wo, Wt);

    const size_t WSTRIDE = (size_t)MH_D * MH_D;
    dim3 gg(N / 128, M / 128);   // (8, 64) -> 512 wg, %8==0 for XCD swizzle
    hipLaunchKernelGGL(gemm_mfma_kernel<0>, gg, dim3(256), 0, stream,
                       xb, Wt + 0 * WSTRIDE, bq, (void*)Qb, M, N, K);
    hipLaunchKernelGGL(gemm_mfma_kernel<0>, gg, dim3(256), 0, stream,
                       xb, Wt + 1 * WSTRIDE, bk, (void*)Kb, M, N, K);
    hipLaunchKernelGGL(gemm_mfma_kernel<2>, gg, dim3(256), 0, stream,
                       xb, Wt + 2 * WSTRIDE, bv, (void*)Vtb, M, N, K);

    hipLaunchKernelGGL(attn_mfma_kernel, dim3(MH_B * MH_H, MH_S / 64), dim3(256),
                       0, stream, Qb, Kb, Vtb, ctx);

    hipLaunchKernelGGL(gemm_mfma_kernel<1>, gg, dim3(256), 0, stream,
                       ctx, Wt + 3 * WSTRIDE, bo, d_out, M, N, K);
}